// Round 6
// baseline (405.876 us; speedup 1.0000x reference)
//
#include <hip/hip_runtime.h>
#include <math.h>

#define NN 100000
#define NE 640000
#define DD 128
#define NBLK 391     // ceil(NN/256)
#define LSTRIDE 132  // 128 + 4 pad, 16B-aligned rows, breaks pow2 stride

typedef __attribute__((ext_vector_type(8))) short short8;   // 8 bf16 = 4 VGPRs
typedef __attribute__((ext_vector_type(4))) float floatx4;  // MFMA C/D

// ---------------- workspace layout (bytes) ----------------
static const size_t OFF_DEG    = 0;        // int[NN]
static const size_t OFF_BSUM   = 400000;   // int[NBLK]
static const size_t OFF_BBASE  = 401600;   // int[NBLK]
static const size_t OFF_DINV   = 403456;   // float[NN]
static const size_t OFF_OFF    = 803456;   // int[NN+1]
static const size_t OFF_CURSOR = 1203712;  // int[NN]
static const size_t OFF_WHP    = 1604096;  // ushort[3*2048*8]
static const size_t OFF_WLP    = 1702400;  // ushort[3*2048*8]
static const size_t OFF_EIDX   = 1800704;  // int[NE]
static const size_t OFF_H      = 4360704;  // float[NN*DD]   (~55.6 MB total)

__device__ __forceinline__ unsigned bf16_rne(float f) {
    unsigned u = __float_as_uint(f);
    return (u + 0x7FFFu + ((u >> 16) & 1u)) >> 16;
}

// ---------------- setup: degree count + W pre-split (merged) ----------------
__global__ __launch_bounds__(256) void count_and_pack(const int* __restrict__ coli,
                                                      int* __restrict__ deg,
                                                      const float* __restrict__ W,
                                                      ushort* __restrict__ Whp,
                                                      ushort* __restrict__ Wlp) {
    int e = blockIdx.x * 256 + threadIdx.x;
    if (e < NE) atomicAdd(&deg[coli[e]], 1);
    if (e < 3 * 2048) {
        int l = e >> 11;
        int r = e & 2047;
        int kc = r >> 9;
        int nt = (r >> 6) & 7;
        int L  = r & 63;
        int n  = nt * 16 + (L & 15);
        int k0 = kc * 32 + (L >> 4) * 8;
        const float* Wl_ = W + (size_t)l * DD * DD;
        size_t base = ((size_t)l * 2048 + r) * 8;
        #pragma unroll
        for (int j = 0; j < 8; ++j) {
            float f = Wl_[(size_t)(k0 + j) * DD + n];
            unsigned hi = bf16_rne(f);
            float fh = __uint_as_float(hi << 16);
            unsigned lo = bf16_rne(f - fh);
            Whp[base + j] = (ushort)hi;
            Wlp[base + j] = (ushort)lo;
        }
    }
}

// ---------------- 3-kernel scan (proven cheap) + dinv fused ----------------
__global__ __launch_bounds__(256) void scan_blocks(const int* __restrict__ deg,
                                                   int* __restrict__ loff,
                                                   int* __restrict__ bsum,
                                                   float* __restrict__ dinv) {
    int tid = threadIdx.x;
    int i = blockIdx.x * 256 + tid;
    int v = (i < NN) ? deg[i] : 0;
    if (i < NN) dinv[i] = (v > 0) ? 1.0f / sqrtf((float)v) : 0.0f;
    int lane = tid & 63, wid = tid >> 6;
    int sv = v;
    #pragma unroll
    for (int s = 1; s < 64; s <<= 1) {
        int t = __shfl_up(sv, s, 64);
        if (lane >= s) sv += t;
    }
    __shared__ int wtot[4];
    if (lane == 63) wtot[wid] = sv;
    __syncthreads();
    if (tid == 0) {
        int r = 0;
        #pragma unroll
        for (int w = 0; w < 4; ++w) { int t = wtot[w]; wtot[w] = r; r += t; }
    }
    __syncthreads();
    int incl = sv + wtot[wid];
    if (i < NN) loff[i] = incl - v;
    if (tid == 255) bsum[blockIdx.x] = incl;
}

__global__ __launch_bounds__(512) void scan_partials(const int* __restrict__ bsum,
                                                     int* __restrict__ bbase,
                                                     int* __restrict__ off) {
    int tid = threadIdx.x;
    int v = (tid < NBLK) ? bsum[tid] : 0;
    int lane = tid & 63, wid = tid >> 6;
    int sv = v;
    #pragma unroll
    for (int s = 1; s < 64; s <<= 1) {
        int t = __shfl_up(sv, s, 64);
        if (lane >= s) sv += t;
    }
    __shared__ int wtot[8];
    if (lane == 63) wtot[wid] = sv;
    __syncthreads();
    if (tid == 0) {
        int r = 0;
        #pragma unroll
        for (int w = 0; w < 8; ++w) { int t = wtot[w]; wtot[w] = r; r += t; }
    }
    __syncthreads();
    int incl = sv + wtot[wid];
    if (tid < NBLK) bbase[tid] = incl - v;
    if (tid == NBLK - 1) off[NN] = incl;
}

__global__ __launch_bounds__(256) void add_base(int* __restrict__ off,
                                                int* __restrict__ cursor,
                                                const int* __restrict__ bbase) {
    int i = blockIdx.x * 256 + threadIdx.x;
    if (i < NN) {
        int v = off[i] + bbase[blockIdx.x];
        off[i] = v;
        cursor[i] = v;
    }
}

__global__ __launch_bounds__(256) void fill_csr(const int* __restrict__ rowi,
                                                const int* __restrict__ coli,
                                                int* __restrict__ cursor,
                                                int* __restrict__ eidx) {
    int e = blockIdx.x * 256 + threadIdx.x;
    if (e < NE) {
        int s = rowi[e], d = coli[e];
        int pos = atomicAdd(&cursor[d], 1);
        eidx[pos] = s;
    }
}

// ---------------- fused layer ----------------
// WEIGHTED=1 (layer 0): gather sums dinv[src]*Xin[src]  (Xin = raw x).
// WEIGHTED=0 (layers 1,2): Xin rows already pre-scaled by dinv at the
//   producing layer's epilogue -> pure row sum, unroll-8, tail corrected by
//   duplicate-load + subtract (all clamped slots load row eidx[e-1]).
// mode=1: store dinv[r]*relu(v)  (pre-scale for next layer). mode=0: plain.
template <int WEIGHTED>
__global__ __launch_bounds__(256) void fused_layer(
        const float* __restrict__ Xin,
        const ushort* __restrict__ Whp,
        const ushort* __restrict__ Wlp,
        const int* __restrict__ off,
        const int* __restrict__ eidx,
        const float* __restrict__ dinv,
        const float* __restrict__ bias,
        float* __restrict__ Y,
        int mode) {
    __shared__ float Ls[32 * LSTRIDE];
    int tid = threadIdx.x;
    int n0 = blockIdx.x * 32;

    // ---- phase 1: gather-aggregate 32 rows into LDS ----
    {
        int g = tid >> 5, lane = tid & 31;
        int c0 = lane * 4;
        #pragma unroll
        for (int t = 0; t < 4; ++t) {
            int nl = g * 4 + t;
            int node = n0 + nl;
            float4 a[8];
            #pragma unroll
            for (int k = 0; k < 8; ++k) a[k] = make_float4(0.f, 0.f, 0.f, 0.f);
            float4 r;
            if (node < NN) {
                int s = off[node];
                int e = off[node + 1];
                float corr = 0.f;
                float4 vlast = make_float4(0.f, 0.f, 0.f, 0.f);
                if (WEIGHTED) {
                    for (int j = s; j < e; j += 8) {
                        int   idx[8];
                        float w[8];
                        #pragma unroll
                        for (int k = 0; k < 8; ++k) {
                            int jj = j + k;
                            idx[k] = eidx[(jj < e) ? jj : s];
                            w[k]   = (jj < e) ? dinv[idx[k]] : 0.f;
                        }
                        float4 v[8];
                        #pragma unroll
                        for (int k = 0; k < 8; ++k)
                            v[k] = *(const float4*)(Xin + (size_t)idx[k] * DD + c0);
                        #pragma unroll
                        for (int k = 0; k < 8; ++k) {
                            a[k].x = fmaf(w[k], v[k].x, a[k].x);
                            a[k].y = fmaf(w[k], v[k].y, a[k].y);
                            a[k].z = fmaf(w[k], v[k].z, a[k].z);
                            a[k].w = fmaf(w[k], v[k].w, a[k].w);
                        }
                    }
                } else {
                    int j = s;
                    for (; j + 8 <= e; j += 8) {
                        int idx[8];
                        #pragma unroll
                        for (int k = 0; k < 8; ++k) idx[k] = eidx[j + k];
                        float4 v[8];
                        #pragma unroll
                        for (int k = 0; k < 8; ++k)
                            v[k] = *(const float4*)(Xin + (size_t)idx[k] * DD + c0);
                        #pragma unroll
                        for (int k = 0; k < 8; ++k) {
                            a[k].x += v[k].x; a[k].y += v[k].y;
                            a[k].z += v[k].z; a[k].w += v[k].w;
                        }
                    }
                    int m = e - j;   // 0..7 remaining
                    if (m > 0) {
                        int idx[8];
                        #pragma unroll
                        for (int k = 0; k < 8; ++k) {
                            int jj = j + k;
                            idx[k] = eidx[(jj < e) ? jj : (e - 1)];
                        }
                        float4 v[8];
                        #pragma unroll
                        for (int k = 0; k < 8; ++k)
                            v[k] = *(const float4*)(Xin + (size_t)idx[k] * DD + c0);
                        #pragma unroll
                        for (int k = 0; k < 8; ++k) {
                            a[k].x += v[k].x; a[k].y += v[k].y;
                            a[k].z += v[k].z; a[k].w += v[k].w;
                        }
                        corr  = (float)(8 - m);   // clamped slots all loaded row eidx[e-1]
                        vlast = v[7];
                    }
                }
                float4 s01 = make_float4(a[0].x + a[1].x, a[0].y + a[1].y,
                                         a[0].z + a[1].z, a[0].w + a[1].w);
                float4 s23 = make_float4(a[2].x + a[3].x, a[2].y + a[3].y,
                                         a[2].z + a[3].z, a[2].w + a[3].w);
                float4 s45 = make_float4(a[4].x + a[5].x, a[4].y + a[5].y,
                                         a[4].z + a[5].z, a[4].w + a[5].w);
                float4 s67 = make_float4(a[6].x + a[7].x, a[6].y + a[7].y,
                                         a[6].z + a[7].z, a[6].w + a[7].w);
                r = make_float4((s01.x + s23.x) + (s45.x + s67.x) - corr * vlast.x,
                                (s01.y + s23.y) + (s45.y + s67.y) - corr * vlast.y,
                                (s01.z + s23.z) + (s45.z + s67.z) - corr * vlast.z,
                                (s01.w + s23.w) + (s45.w + s67.w) - corr * vlast.w);
            } else {
                r = make_float4(0.f, 0.f, 0.f, 0.f);
            }
            *(float4*)(&Ls[nl * LSTRIDE + c0]) = r;
        }
    }
    __syncthreads();

    // ---- phase 2: split-bf16 MFMA; wave w: row tile mt=w>>1, col tiles nh..nh+3 ----
    int wave = tid >> 6;
    int lane = tid & 63;
    int m    = lane & 15;
    int quad = lane >> 4;
    int mt   = wave >> 1;
    int nh   = (wave & 1) * 4;

    floatx4 acc[4];
    #pragma unroll
    for (int q = 0; q < 4; ++q) acc[q] = (floatx4){0.f, 0.f, 0.f, 0.f};

    #pragma unroll
    for (int kc = 0; kc < 4; ++kc) {
        const float* lp = &Ls[(mt * 16 + m) * LSTRIDE + kc * 32 + quad * 8];
        float4 xa = *(const float4*)(lp);
        float4 xb = *(const float4*)(lp + 4);
        float xs[8] = {xa.x, xa.y, xa.z, xa.w, xb.x, xb.y, xb.z, xb.w};
        short8 ah, al;
        #pragma unroll
        for (int j = 0; j < 8; ++j) {
            unsigned hi = bf16_rne(xs[j]);
            float fh = __uint_as_float(hi << 16);
            unsigned lo = bf16_rne(xs[j] - fh);
            ah[j] = (short)hi;
            al[j] = (short)lo;
        }
        #pragma unroll
        for (int q = 0; q < 4; ++q) {
            int nt = nh + q;
            size_t fidx = (((size_t)(kc * 8 + nt)) * 64 + lane) * 8;
            short8 bh = *(const short8*)(Whp + fidx);
            short8 bl = *(const short8*)(Wlp + fidx);
            acc[q] = __builtin_amdgcn_mfma_f32_16x16x32_bf16(al, bh, acc[q], 0, 0, 0);
            acc[q] = __builtin_amdgcn_mfma_f32_16x16x32_bf16(ah, bl, acc[q], 0, 0, 0);
            acc[q] = __builtin_amdgcn_mfma_f32_16x16x32_bf16(ah, bh, acc[q], 0, 0, 0);
        }
    }

    // C/D: col = nt*16 + m, row = n0 + mt*16 + quad*4 + i
    #pragma unroll
    for (int i = 0; i < 4; ++i) {
        int ro = n0 + mt * 16 + quad * 4 + i;
        if (ro < NN) {
            float s = dinv[ro];
            #pragma unroll
            for (int q = 0; q < 4; ++q) {
                int col = (nh + q) * 16 + m;
                float v = acc[q][i] * s + bias[col];
                if (mode) v = fmaxf(v, 0.f) * s;   // relu + pre-scale for next layer
                Y[(size_t)ro * DD + col] = v;
            }
        }
    }
}

// ---------------- launch ----------------

extern "C" void kernel_launch(void* const* d_in, const int* in_sizes, int n_in,
                              void* d_out, int out_size, void* d_ws, size_t ws_size,
                              hipStream_t stream) {
    const float* x  = (const float*)d_in[0];
    const int*   ei = (const int*)d_in[1];   // [2, NE] flattened, int32
    const float* W  = (const float*)d_in[3]; // [3, DD, DD]
    const float* b  = (const float*)d_in[4]; // [3, DD]
    float* out = (float*)d_out;

    char* ws = (char*)d_ws;
    int*    deg    = (int*)(ws + OFF_DEG);
    int*    bsum   = (int*)(ws + OFF_BSUM);
    int*    bbase  = (int*)(ws + OFF_BBASE);
    float*  dinv   = (float*)(ws + OFF_DINV);
    int*    off    = (int*)(ws + OFF_OFF);
    int*    cursor = (int*)(ws + OFF_CURSOR);
    ushort* whp    = (ushort*)(ws + OFF_WHP);
    ushort* wlp    = (ushort*)(ws + OFF_WLP);
    int*    eidx   = (int*)(ws + OFF_EIDX);
    float*  H      = (float*)(ws + OFF_H);

    const int* rowi = ei;        // sources
    const int* coli = ei + NE;   // targets

    // --- setup ---
    hipMemsetAsync(deg, 0, NN * sizeof(int), stream);
    count_and_pack<<<(NE + 255) / 256, 256, 0, stream>>>(coli, deg, W, whp, wlp);
    scan_blocks<<<NBLK, 256, 0, stream>>>(deg, off, bsum, dinv);
    scan_partials<<<1, 512, 0, stream>>>(bsum, bbase, off);
    add_base<<<NBLK, 256, 0, stream>>>(off, cursor, bbase);
    fill_csr<<<(NE + 255) / 256, 256, 0, stream>>>(rowi, coli, cursor, eidx);

    // --- 3 fused layers; chain x -> out(scaled) -> H(scaled) -> out(final) ---
    int nblk = (NN + 31) / 32;
    fused_layer<1><<<nblk, 256, 0, stream>>>(x,   whp,         wlp,         off, eidx,
                                             dinv, b,          out, 1);
    fused_layer<0><<<nblk, 256, 0, stream>>>(out, whp + 16384, wlp + 16384, off, eidx,
                                             dinv, b + DD,     H,   1);
    fused_layer<0><<<nblk, 256, 0, stream>>>(H,   whp + 32768, wlp + 32768, off, eidx,
                                             dinv, b + 2 * DD, out, 0);
}

// Round 7
// 374.899 us; speedup vs baseline: 1.0826x; 1.0826x over previous
//
#include <hip/hip_runtime.h>
#include <math.h>

#define NN 100000
#define NE 640000
#define DD 128
#define NBLK 391     // ceil(NN/256)
#define LSTRIDE 132  // 128 + 4 pad, 16B-aligned rows, breaks pow2 stride

typedef __attribute__((ext_vector_type(8))) short short8;   // 8 bf16 = 4 VGPRs
typedef __attribute__((ext_vector_type(4))) float floatx4;  // MFMA C/D

// ---------------- workspace layout (bytes) ----------------
static const size_t OFF_DEG    = 0;        // int[NN]
static const size_t OFF_BSUM   = 400000;   // int[NBLK]
static const size_t OFF_BBASE  = 401600;   // int[NBLK]
static const size_t OFF_DINV   = 403456;   // float[NN]
static const size_t OFF_OFF    = 803456;   // int[NN+1]
static const size_t OFF_CURSOR = 1203712;  // int[NN]
static const size_t OFF_WHP    = 1604096;  // ushort[3*2048*8]
static const size_t OFF_WLP    = 1702400;  // ushort[3*2048*8]
static const size_t OFF_EIDX   = 1800704;  // int[NE]
static const size_t OFF_H      = 4360704;  // float[NN*DD]   (~55.6 MB total)

__device__ __forceinline__ unsigned bf16_rne(float f) {
    unsigned u = __float_as_uint(f);
    return (u + 0x7FFFu + ((u >> 16) & 1u)) >> 16;
}

// ---------------- setup: degree count + W pre-split (merged) ----------------
__global__ __launch_bounds__(256) void count_and_pack(const int* __restrict__ coli,
                                                      int* __restrict__ deg,
                                                      const float* __restrict__ W,
                                                      ushort* __restrict__ Whp,
                                                      ushort* __restrict__ Wlp) {
    int e = blockIdx.x * 256 + threadIdx.x;
    if (e < NE) atomicAdd(&deg[coli[e]], 1);
    if (e < 3 * 2048) {
        int l = e >> 11;
        int r = e & 2047;
        int kc = r >> 9;
        int nt = (r >> 6) & 7;
        int L  = r & 63;
        int n  = nt * 16 + (L & 15);
        int k0 = kc * 32 + (L >> 4) * 8;
        const float* Wl_ = W + (size_t)l * DD * DD;
        size_t base = ((size_t)l * 2048 + r) * 8;
        #pragma unroll
        for (int j = 0; j < 8; ++j) {
            float f = Wl_[(size_t)(k0 + j) * DD + n];
            unsigned hi = bf16_rne(f);
            float fh = __uint_as_float(hi << 16);
            unsigned lo = bf16_rne(f - fh);
            Whp[base + j] = (ushort)hi;
            Wlp[base + j] = (ushort)lo;
        }
    }
}

// ---------------- 3-kernel scan (proven cheap) + dinv fused ----------------
__global__ __launch_bounds__(256) void scan_blocks(const int* __restrict__ deg,
                                                   int* __restrict__ loff,
                                                   int* __restrict__ bsum,
                                                   float* __restrict__ dinv) {
    int tid = threadIdx.x;
    int i = blockIdx.x * 256 + tid;
    int v = (i < NN) ? deg[i] : 0;
    if (i < NN) dinv[i] = (v > 0) ? 1.0f / sqrtf((float)v) : 0.0f;
    int lane = tid & 63, wid = tid >> 6;
    int sv = v;
    #pragma unroll
    for (int s = 1; s < 64; s <<= 1) {
        int t = __shfl_up(sv, s, 64);
        if (lane >= s) sv += t;
    }
    __shared__ int wtot[4];
    if (lane == 63) wtot[wid] = sv;
    __syncthreads();
    if (tid == 0) {
        int r = 0;
        #pragma unroll
        for (int w = 0; w < 4; ++w) { int t = wtot[w]; wtot[w] = r; r += t; }
    }
    __syncthreads();
    int incl = sv + wtot[wid];
    if (i < NN) loff[i] = incl - v;
    if (tid == 255) bsum[blockIdx.x] = incl;
}

__global__ __launch_bounds__(512) void scan_partials(const int* __restrict__ bsum,
                                                     int* __restrict__ bbase,
                                                     int* __restrict__ off) {
    int tid = threadIdx.x;
    int v = (tid < NBLK) ? bsum[tid] : 0;
    int lane = tid & 63, wid = tid >> 6;
    int sv = v;
    #pragma unroll
    for (int s = 1; s < 64; s <<= 1) {
        int t = __shfl_up(sv, s, 64);
        if (lane >= s) sv += t;
    }
    __shared__ int wtot[8];
    if (lane == 63) wtot[wid] = sv;
    __syncthreads();
    if (tid == 0) {
        int r = 0;
        #pragma unroll
        for (int w = 0; w < 8; ++w) { int t = wtot[w]; wtot[w] = r; r += t; }
    }
    __syncthreads();
    int incl = sv + wtot[wid];
    if (tid < NBLK) bbase[tid] = incl - v;
    if (tid == NBLK - 1) off[NN] = incl;
}

__global__ __launch_bounds__(256) void add_base(int* __restrict__ off,
                                                int* __restrict__ cursor,
                                                const int* __restrict__ bbase) {
    int i = blockIdx.x * 256 + threadIdx.x;
    if (i < NN) {
        int v = off[i] + bbase[blockIdx.x];
        off[i] = v;
        cursor[i] = v;
    }
}

__global__ __launch_bounds__(256) void fill_csr(const int* __restrict__ rowi,
                                                const int* __restrict__ coli,
                                                int* __restrict__ cursor,
                                                int* __restrict__ eidx) {
    int e = blockIdx.x * 256 + threadIdx.x;
    if (e < NE) {
        int s = rowi[e], d = coli[e];
        int pos = atomicAdd(&cursor[d], 1);
        eidx[pos] = s;
    }
}

// ---------------- fused layer: Y = relu?( dinv*(A_gather(Xin)) @ W + b ) ----
// A(XW) == (AX)W. 32 dst nodes / 256-thread block, LDS 16.9 KB.
// Phase 1: 8 groups x 4 nodes; predicated width-8 edge groups (index-clamp +
// w=0 masking, no tail path) -> 8 simultaneously-outstanding 16B gathers.
// Explicit scalar regs only (v0..v7, a0..a3) to avoid scratch demotion.
// Phase 2: 2x8 grid of 16x16 MFMA tiles split 4-per-wave across 4 waves.
__global__ __launch_bounds__(256) void fused_layer(
        const float* __restrict__ Xin,
        const ushort* __restrict__ Whp,
        const ushort* __restrict__ Wlp,
        const int* __restrict__ off,
        const int* __restrict__ eidx,
        const float* __restrict__ dinv,
        const float* __restrict__ bias,
        float* __restrict__ Y,
        int do_relu) {
    __shared__ float Ls[32 * LSTRIDE];
    int tid = threadIdx.x;
    int n0 = blockIdx.x * 32;

    // ---- phase 1: gather-aggregate 32 rows of dinv[src]*Xin[src] into LDS ----
    {
        int g = tid >> 5, lane = tid & 31;
        int c0 = lane * 4;
        #pragma unroll
        for (int t = 0; t < 4; ++t) {
            int nl = g * 4 + t;
            int node = n0 + nl;
            float4 a0 = make_float4(0.f, 0.f, 0.f, 0.f);
            float4 a1 = a0, a2 = a0, a3 = a0;
            if (node < NN) {
                int s = off[node];
                int e = off[node + 1];
                for (int j = s; j < e; j += 8) {
                    int j1 = j + 1, j2 = j + 2, j3 = j + 3;
                    int j4 = j + 4, j5 = j + 5, j6 = j + 6, j7 = j + 7;
                    int i0 = eidx[j];
                    int i1 = eidx[(j1 < e) ? j1 : j];
                    int i2 = eidx[(j2 < e) ? j2 : j];
                    int i3 = eidx[(j3 < e) ? j3 : j];
                    int i4 = eidx[(j4 < e) ? j4 : j];
                    int i5 = eidx[(j5 < e) ? j5 : j];
                    int i6 = eidx[(j6 < e) ? j6 : j];
                    int i7 = eidx[(j7 < e) ? j7 : j];
                    float w0 = dinv[i0];
                    float w1 = (j1 < e) ? dinv[i1] : 0.f;
                    float w2 = (j2 < e) ? dinv[i2] : 0.f;
                    float w3 = (j3 < e) ? dinv[i3] : 0.f;
                    float w4 = (j4 < e) ? dinv[i4] : 0.f;
                    float w5 = (j5 < e) ? dinv[i5] : 0.f;
                    float w6 = (j6 < e) ? dinv[i6] : 0.f;
                    float w7 = (j7 < e) ? dinv[i7] : 0.f;
                    float4 v0 = *(const float4*)(Xin + (size_t)i0 * DD + c0);
                    float4 v1 = *(const float4*)(Xin + (size_t)i1 * DD + c0);
                    float4 v2 = *(const float4*)(Xin + (size_t)i2 * DD + c0);
                    float4 v3 = *(const float4*)(Xin + (size_t)i3 * DD + c0);
                    float4 v4 = *(const float4*)(Xin + (size_t)i4 * DD + c0);
                    float4 v5 = *(const float4*)(Xin + (size_t)i5 * DD + c0);
                    float4 v6 = *(const float4*)(Xin + (size_t)i6 * DD + c0);
                    float4 v7 = *(const float4*)(Xin + (size_t)i7 * DD + c0);
                    a0.x = fmaf(w0, v0.x, a0.x); a0.y = fmaf(w0, v0.y, a0.y);
                    a0.z = fmaf(w0, v0.z, a0.z); a0.w = fmaf(w0, v0.w, a0.w);
                    a1.x = fmaf(w1, v1.x, a1.x); a1.y = fmaf(w1, v1.y, a1.y);
                    a1.z = fmaf(w1, v1.z, a1.z); a1.w = fmaf(w1, v1.w, a1.w);
                    a2.x = fmaf(w2, v2.x, a2.x); a2.y = fmaf(w2, v2.y, a2.y);
                    a2.z = fmaf(w2, v2.z, a2.z); a2.w = fmaf(w2, v2.w, a2.w);
                    a3.x = fmaf(w3, v3.x, a3.x); a3.y = fmaf(w3, v3.y, a3.y);
                    a3.z = fmaf(w3, v3.z, a3.z); a3.w = fmaf(w3, v3.w, a3.w);
                    a0.x = fmaf(w4, v4.x, a0.x); a0.y = fmaf(w4, v4.y, a0.y);
                    a0.z = fmaf(w4, v4.z, a0.z); a0.w = fmaf(w4, v4.w, a0.w);
                    a1.x = fmaf(w5, v5.x, a1.x); a1.y = fmaf(w5, v5.y, a1.y);
                    a1.z = fmaf(w5, v5.z, a1.z); a1.w = fmaf(w5, v5.w, a1.w);
                    a2.x = fmaf(w6, v6.x, a2.x); a2.y = fmaf(w6, v6.y, a2.y);
                    a2.z = fmaf(w6, v6.z, a2.z); a2.w = fmaf(w6, v6.w, a2.w);
                    a3.x = fmaf(w7, v7.x, a3.x); a3.y = fmaf(w7, v7.y, a3.y);
                    a3.z = fmaf(w7, v7.z, a3.z); a3.w = fmaf(w7, v7.w, a3.w);
                }
            }
            float4 r = make_float4((a0.x + a1.x) + (a2.x + a3.x),
                                   (a0.y + a1.y) + (a2.y + a3.y),
                                   (a0.z + a1.z) + (a2.z + a3.z),
                                   (a0.w + a1.w) + (a2.w + a3.w));
            *(float4*)(&Ls[nl * LSTRIDE + c0]) = r;
        }
    }
    __syncthreads();

    // ---- phase 2: split-bf16 MFMA; wave w: row tile mt=w>>1, col tiles nh..nh+3 ----
    int wave = tid >> 6;
    int lane = tid & 63;
    int m    = lane & 15;
    int quad = lane >> 4;
    int mt   = wave >> 1;
    int nh   = (wave & 1) * 4;

    floatx4 acc[4];
    #pragma unroll
    for (int q = 0; q < 4; ++q) acc[q] = (floatx4){0.f, 0.f, 0.f, 0.f};

    #pragma unroll
    for (int kc = 0; kc < 4; ++kc) {
        const float* lp = &Ls[(mt * 16 + m) * LSTRIDE + kc * 32 + quad * 8];
        float4 xa = *(const float4*)(lp);
        float4 xb = *(const float4*)(lp + 4);
        float xs[8] = {xa.x, xa.y, xa.z, xa.w, xb.x, xb.y, xb.z, xb.w};
        short8 ah, al;
        #pragma unroll
        for (int j = 0; j < 8; ++j) {
            unsigned hi = bf16_rne(xs[j]);
            float fh = __uint_as_float(hi << 16);
            unsigned lo = bf16_rne(xs[j] - fh);
            ah[j] = (short)hi;
            al[j] = (short)lo;
        }
        #pragma unroll
        for (int q = 0; q < 4; ++q) {
            int nt = nh + q;
            size_t fidx = (((size_t)(kc * 8 + nt)) * 64 + lane) * 8;
            short8 bh = *(const short8*)(Whp + fidx);
            short8 bl = *(const short8*)(Wlp + fidx);
            acc[q] = __builtin_amdgcn_mfma_f32_16x16x32_bf16(al, bh, acc[q], 0, 0, 0);
            acc[q] = __builtin_amdgcn_mfma_f32_16x16x32_bf16(ah, bl, acc[q], 0, 0, 0);
            acc[q] = __builtin_amdgcn_mfma_f32_16x16x32_bf16(ah, bh, acc[q], 0, 0, 0);
        }
    }

    // C/D: col = nt*16 + m, row = n0 + mt*16 + quad*4 + i
    #pragma unroll
    for (int i = 0; i < 4; ++i) {
        int ro = n0 + mt * 16 + quad * 4 + i;
        if (ro < NN) {
            float s = dinv[ro];
            #pragma unroll
            for (int q = 0; q < 4; ++q) {
                int col = (nh + q) * 16 + m;
                float v = acc[q][i] * s + bias[col];
                if (do_relu) v = fmaxf(v, 0.f);
                Y[(size_t)ro * DD + col] = v;
            }
        }
    }
}

// ---------------- launch ----------------

extern "C" void kernel_launch(void* const* d_in, const int* in_sizes, int n_in,
                              void* d_out, int out_size, void* d_ws, size_t ws_size,
                              hipStream_t stream) {
    const float* x  = (const float*)d_in[0];
    const int*   ei = (const int*)d_in[1];   // [2, NE] flattened, int32
    const float* W  = (const float*)d_in[3]; // [3, DD, DD]
    const float* b  = (const float*)d_in[4]; // [3, DD]
    float* out = (float*)d_out;

    char* ws = (char*)d_ws;
    int*    deg    = (int*)(ws + OFF_DEG);
    int*    bsum   = (int*)(ws + OFF_BSUM);
    int*    bbase  = (int*)(ws + OFF_BBASE);
    float*  dinv   = (float*)(ws + OFF_DINV);
    int*    off    = (int*)(ws + OFF_OFF);
    int*    cursor = (int*)(ws + OFF_CURSOR);
    ushort* whp    = (ushort*)(ws + OFF_WHP);
    ushort* wlp    = (ushort*)(ws + OFF_WLP);
    int*    eidx   = (int*)(ws + OFF_EIDX);
    float*  H      = (float*)(ws + OFF_H);

    const int* rowi = ei;        // sources
    const int* coli = ei + NE;   // targets

    // --- setup ---
    hipMemsetAsync(deg, 0, NN * sizeof(int), stream);
    count_and_pack<<<(NE + 255) / 256, 256, 0, stream>>>(coli, deg, W, whp, wlp);
    scan_blocks<<<NBLK, 256, 0, stream>>>(deg, off, bsum, dinv);
    scan_partials<<<1, 512, 0, stream>>>(bsum, bbase, off);
    add_base<<<NBLK, 256, 0, stream>>>(off, cursor, bbase);
    fill_csr<<<(NE + 255) / 256, 256, 0, stream>>>(rowi, coli, cursor, eidx);

    // --- 3 fused layers; buffer chain x -> out -> H -> out (no RW races) ---
    int nblk = (NN + 31) / 32;
    fused_layer<<<nblk, 256, 0, stream>>>(x,   whp,         wlp,         off, eidx,
                                          dinv, b,          out, 1);
    fused_layer<<<nblk, 256, 0, stream>>>(out, whp + 16384, wlp + 16384, off, eidx,
                                          dinv, b + DD,     H,   1);
    fused_layer<<<nblk, 256, 0, stream>>>(H,   whp + 32768, wlp + 32768, off, eidx,
                                          dinv, b + 2 * DD, out, 0);
}